// Round 7
// baseline (87.012 us; speedup 1.0000x reference)
//
#include <hip/hip_runtime.h>

// Log-signature depth 3, d=8, L=256, B=2048 — single fused kernel.
// V7: 8 waves × 32 steps (was 4 × 64). V6 halved LDS traffic with zero
// effect -> scan is NOT per-CU-throughput bound; hypothesis: per-wave
// SERIAL latency bound (64 dependent steps, lockstep waves). This version
// keeps V6's data layout byte-for-byte (fp16 broadcast rows consumed via
// inline-asm v_fma_mix_f32; fp32 transposed dxT for exact dxi/dxj) and
// halves only the serial depth. Per-CU totals unchanged: 512 thr/block,
// 4 blocks/CU = 32 waves/CU.
//   chunk scan (per wave, 32 steps, old state on RHS):
//     S3[i][j][k] += (S2[i][j] + (0.5*S1[i] + dx[i]/6)*dx[j]) * dx[k]
//     S2[i][j]    += (S1[i] + 0.5*dx[i]) * dx[j]
//     S1[i]       += dx[i]
//   fold (wave 0, c=1..7): C1=A1+B1; C2=A2+B2+A1⊗B1; C3=A3+B3+A1⊗B2+A2⊗B1.
// dxT (8.3K) + dxh (4K) overlay sig3 (16K) — disjoint lifetimes, barrier.

#define LEN 256
#define DCH 8
#define NW 8
#define NTHREADS (NW * 64)
#define CHUNK (LEN / NW)      // 32 steps per wave
#define OUTSTRIDE (DCH + DCH*DCH + DCH*DCH*DCH)  // 584
#define TSTRIDE 260           // dxT row stride in floats: conflict-free starts
#define DXT_BYTES (DCH * TSTRIDE * 4)            // 8320
#define POOL_BYTES (NW * 512 * 4)                // 16384 (sig3 view)

typedef float f4v __attribute__((ext_vector_type(4)));
typedef _Float16 h4 __attribute__((ext_vector_type(4)));

// acc += wv * f16(lo/hi half of dw)   — VOP3P mixed-precision FMA
#define MIX_LO(acc, wv, dw) \
    asm("v_fma_mix_f32 %0, %1, %2, %0 op_sel:[0,0,0] op_sel_hi:[0,1,0]" \
        : "+v"(acc) : "v"(wv), "v"(dw))
#define MIX_HI(acc, wv, dw) \
    asm("v_fma_mix_f32 %0, %1, %2, %0 op_sel:[0,1,0] op_sel_hi:[0,1,0]" \
        : "+v"(acc) : "v"(wv), "v"(dw))

__global__ __launch_bounds__(NTHREADS) void logsig_fused(const float* __restrict__ x,
                                                         float* __restrict__ out) {
    // pool: [dxT 8320B | dxh 4096B] (scan phase) OVERLAID WITH sig3 16384B (fold)
    __shared__ __align__(16) unsigned char pool[POOL_BYTES];
    __shared__ __align__(16) float sig1[NW][8];
    __shared__ __align__(16) float sig2[NW][64];
    __shared__ __align__(16) float s1buf[8];
    __shared__ __align__(16) float s2buf[64];

    float* dxT = (float*)pool;                             // scan-phase view
    _Float16* dxh = (_Float16*)(pool + DXT_BYTES);         // scan-phase view
    float (*sig3)[512] = (float(*)[512])pool;              // fold-phase view

    const int tid  = threadIdx.x;
    const int w    = tid >> 6;
    const int lane = tid & 63;
    const int i    = lane >> 3;
    const int j    = lane & 7;
    const int b    = blockIdx.x;

    // ---- Stage dx = x[t+1]-x[t]: fp16 rows (dxh) + fp32 transposed (dxT) ----
    {
        const float4* x4 = (const float4*)(x + (size_t)b * (LEN * DCH));
        const int f = tid;                 // 512 threads, one pass
        float4 dv;
        if (f < 510) {
            float4 a = x4[f];
            float4 c = x4[f + 2];
            dv.x = c.x - a.x; dv.y = c.y - a.y; dv.z = c.z - a.z; dv.w = c.w - a.w;
        } else {
            dv.x = 0.f; dv.y = 0.f; dv.z = 0.f; dv.w = 0.f;  // zero row t=255
        }
        const int t  = f >> 1;
        const int cg = (f & 1) * 4;
        h4 hv = { (_Float16)dv.x, (_Float16)dv.y, (_Float16)dv.z, (_Float16)dv.w };
        *(h4*)&dxh[t * DCH + cg] = hv;                // ds_write_b64
        dxT[(cg + 0) * TSTRIDE + t] = dv.x;           // 4× ds_write_b32, ≤2-way
        dxT[(cg + 1) * TSTRIDE + t] = dv.y;
        dxT[(cg + 2) * TSTRIDE + t] = dv.z;
        dxT[(cg + 3) * TSTRIDE + t] = dv.w;
    }
    __syncthreads();

    // ---- Chunk scan: 32 steps per wave ----
    float s1 = 0.f, s2 = 0.f;
    float s3[8];
#pragma unroll
    for (int k = 0; k < 8; ++k) s3[k] = 0.f;

    const float c6 = 1.f / 6.f;
    const int cb = w * CHUNK;
    const uint32_t* hrow = (const uint32_t*)&dxh[cb * DCH];  // 4 dwords per row
    const float* ti = dxT + i * TSTRIDE + cb;
    const float* tj = dxT + j * TSTRIDE + cb;

    for (int g = 0; g < CHUNK / 4; ++g) {
        f4v qi = *(const f4v*)(ti + g * 4);   // ds_read_b128, conflict-free
        f4v qj = *(const f4v*)(tj + g * 4);   // ds_read_b128, conflict-free
#pragma unroll
        for (int u = 0; u < 4; ++u) {
            const int t = g * 4 + u;
            uint4 rw = *(const uint4*)(hrow + t * 4);   // broadcast ds_read_b128
            const float dxi = qi[u];                    // reg, compile-time idx
            const float dxj = qj[u];
            const float tt = fmaf(c6, dxi, 0.5f * s1);
            float w3 = fmaf(tt, dxj, s2);
            MIX_LO(s3[0], w3, rw.x);  MIX_HI(s3[1], w3, rw.x);
            MIX_LO(s3[2], w3, rw.y);  MIX_HI(s3[3], w3, rw.y);
            MIX_LO(s3[4], w3, rw.z);  MIX_HI(s3[5], w3, rw.z);
            MIX_LO(s3[6], w3, rw.w);  MIX_HI(s3[7], w3, rw.w);
            const float uu = fmaf(0.5f, dxi, s1);
            s2 = fmaf(uu, dxj, s2);
            s1 += dxi;
        }
    }

    // dxT/dxh are read by all waves during scan; sig3 overlays them.
    __syncthreads();

    // ---- Publish chunk signatures ----
    if (j == 0) sig1[w][i] = s1;
    sig2[w][lane] = s2;
    float* sp = &sig3[w][lane * 8];
    *(float4*)(sp)     = make_float4(s3[0], s3[1], s3[2], s3[3]);
    *(float4*)(sp + 4) = make_float4(s3[4], s3[5], s3[6], s3[7]);
    __syncthreads();

    if (w != 0) return;

    // ---- Fold chunks 1..7 into wave 0's registers (A=accum, B=chunk c) ----
    for (int c = 1; c < NW; ++c) {
        float B1i  = sig1[c][i];
        float B1j  = sig1[c][j];
        float B2ij = sig2[c][lane];
        float4 b1a = *(const float4*)&sig1[c][0];
        float4 b1b = *(const float4*)&sig1[c][4];
        const float* b2row = &sig2[c][j * 8];
        float4 b2a = *(const float4*)(b2row);
        float4 b2b = *(const float4*)(b2row + 4);
        const float* b3row = &sig3[c][lane * 8];
        float4 b3a = *(const float4*)(b3row);
        float4 b3b = *(const float4*)(b3row + 4);
        float B1k[8]  = {b1a.x, b1a.y, b1a.z, b1a.w, b1b.x, b1b.y, b1b.z, b1b.w};
        float B2jk[8] = {b2a.x, b2a.y, b2a.z, b2a.w, b2b.x, b2b.y, b2b.z, b2b.w};
        float B3[8]   = {b3a.x, b3a.y, b3a.z, b3a.w, b3b.x, b3b.y, b3b.z, b3b.w};
#pragma unroll
        for (int k = 0; k < 8; ++k)   // uses OLD s1 (A1), OLD s2 (A2)
            s3[k] = s3[k] + B3[k] + s1 * B2jk[k] + s2 * B1k[k];
        s2 = s2 + B2ij + s1 * B1j;    // uses OLD s1
        s1 = s1 + B1i;
    }

    // ---- Log map epilogue (wave-internal LDS exchange) ----
    if (j == 0) s1buf[i] = s1;
    s2buf[lane] = s2;

    float S1r[8], S2rj[8];
#pragma unroll
    for (int k = 0; k < 8; ++k) S1r[k] = s1buf[k];
#pragma unroll
    for (int k = 0; k < 8; ++k) S2rj[k] = s2buf[j * 8 + k];
    float s1j = s1buf[j];

    float* ob = out + (size_t)b * OUTSTRIDE;
    if (lane < 8) ob[lane] = s1buf[lane];            // l1
    ob[8 + lane] = fmaf(-0.5f * s1, s1j, s2);        // l2

    float c3 = (1.f / 3.f) * s1 * s1j;
    float l3[8];
#pragma unroll
    for (int k = 0; k < 8; ++k)
        l3[k] = s3[k] - 0.5f * (s1 * S2rj[k] + s2 * S1r[k]) + c3 * S1r[k];
    float* p3 = ob + 72 + lane * 8;
    *(float4*)(p3)     = make_float4(l3[0], l3[1], l3[2], l3[3]);
    *(float4*)(p3 + 4) = make_float4(l3[4], l3[5], l3[6], l3[7]);
}

extern "C" void kernel_launch(void* const* d_in, const int* in_sizes, int n_in,
                              void* d_out, int out_size, void* d_ws, size_t ws_size,
                              hipStream_t stream) {
    const float* x = (const float*)d_in[0];
    float* out = (float*)d_out;
    const int B = in_sizes[0] / (LEN * DCH);   // 2048
    hipLaunchKernelGGL(logsig_fused, dim3(B), dim3(NTHREADS), 0, stream, x, out);
}

// Round 8
// 73.613 us; speedup vs baseline: 1.1820x; 1.1820x over previous
//
#include <hip/hip_runtime.h>

// Log-signature depth 3, d=8, L=256, B=2048 — single fused kernel.
// One block (4 waves) per batch element. Time split into 4 chunks of 64
// steps; each wave scans its chunk from zero state (dx row t=255 is zeroed,
// a Chen identity step). Chunk signatures are then folded left-to-right by
// wave 0 using Chen's rule:
//   C1 = A1+B1;  C2 = A2+B2+A1⊗B1;  C3 = A3+B3+A1⊗B2+A2⊗B1.
// Lane l = (i=l>>3, j=l&7); per-lane state s1=S1[i], s2=S2[i][j],
// s3[k]=S3[i][j][k]. Per scan step (old state on RHS):
//   S3[i][j][k] += (S2[i][j] + (0.5*S1[i] + dx[i]/6)*dx[j]) * dx[k]
//   S2[i][j]    += (S1[i] + 0.5*dx[i]) * dx[j]
//   S1[i]       += dx[i]
//
// FINAL (V8 = V1 restored): session post-mortem. V2 (global row), V3
// (readlane row), V4 (cndmask extract), V5/V6 (fp16 row via v_fma_mix,
// transposed fp32 quads — verifiably ~half the LDS cycles), V7 (8 waves
// × 32 steps) ALL matched or regressed vs this structure. The scan is
// not LDS-throughput, not VALU-throughput, not serial-latency bound per
// those ablations; the harness fill (~42.6us @ 79% HBM peak) plus this
// ~30us kernel is the measured floor. Keep this exact loop shape — the
// compiler's pipelining of the 2 broadcast ds_read_b128 + 2 ds_read_b32
// per step is the best schedule found in 8 rounds.

#define LEN 256
#define DCH 8
#define NW 4
#define CHUNK (LEN / NW)      // 64 steps per wave
#define OUTSTRIDE (DCH + DCH*DCH + DCH*DCH*DCH)  // 584

__global__ __launch_bounds__(256) void logsig_fused(const float* __restrict__ x,
                                                    float* __restrict__ out) {
    __shared__ __align__(16) float dxbuf[LEN][DCH];   // 8 KB
    __shared__ __align__(16) float sig1[NW][8];
    __shared__ __align__(16) float sig2[NW][64];
    __shared__ __align__(16) float sig3[NW][512];
    __shared__ __align__(16) float s1buf[8];
    __shared__ __align__(16) float s2buf[64];

    const int tid  = threadIdx.x;
    const int w    = tid >> 6;
    const int lane = tid & 63;
    const int i    = lane >> 3;
    const int j    = lane & 7;
    const int b    = blockIdx.x;

    // ---- Stage dx = x[t+1]-x[t] into LDS (coalesced float4) ----
    const float4* x4 = (const float4*)(x + (size_t)b * (LEN * DCH));
    float4* d4 = (float4*)&dxbuf[0][0];
    for (int f = tid; f < 512; f += 256) {
        float4 dv;
        if (f < 510) {
            float4 a = x4[f];
            float4 c = x4[f + 2];
            dv.x = c.x - a.x; dv.y = c.y - a.y; dv.z = c.z - a.z; dv.w = c.w - a.w;
        } else {
            dv.x = 0.f; dv.y = 0.f; dv.z = 0.f; dv.w = 0.f;  // zero row t=255
        }
        d4[f] = dv;
    }
    __syncthreads();

    // ---- Chunk scan: 64 steps per wave ----
    float s1 = 0.f, s2 = 0.f;
    float s3[8];
#pragma unroll
    for (int k = 0; k < 8; ++k) s3[k] = 0.f;

    const float c6 = 1.f / 6.f;
    const float* base = &dxbuf[w * CHUNK][0];
    for (int tb = 0; tb < CHUNK; tb += 4) {
#pragma unroll
        for (int u = 0; u < 4; ++u) {
            const float* row = base + (tb + u) * 8;
            float4 r0 = *(const float4*)(row);       // broadcast b128
            float4 r1 = *(const float4*)(row + 4);   // broadcast b128
            float dxi = row[i];                      // 8 addr, 8-way bcast
            float dxj = row[j];
            float tt = fmaf(c6, dxi, 0.5f * s1);
            float w3 = fmaf(tt, dxj, s2);
            s3[0] = fmaf(w3, r0.x, s3[0]);
            s3[1] = fmaf(w3, r0.y, s3[1]);
            s3[2] = fmaf(w3, r0.z, s3[2]);
            s3[3] = fmaf(w3, r0.w, s3[3]);
            s3[4] = fmaf(w3, r1.x, s3[4]);
            s3[5] = fmaf(w3, r1.y, s3[5]);
            s3[6] = fmaf(w3, r1.z, s3[6]);
            s3[7] = fmaf(w3, r1.w, s3[7]);
            float uu = fmaf(0.5f, dxi, s1);
            s2 = fmaf(uu, dxj, s2);
            s1 += dxi;
        }
    }

    // ---- Publish chunk signatures ----
    if (j == 0) sig1[w][i] = s1;
    sig2[w][lane] = s2;
    float* sp = &sig3[w][lane * 8];
    *(float4*)(sp)     = make_float4(s3[0], s3[1], s3[2], s3[3]);
    *(float4*)(sp + 4) = make_float4(s3[4], s3[5], s3[6], s3[7]);
    __syncthreads();

    if (w != 0) return;

    // ---- Fold chunks 1..3 into wave 0's registers (A=accum, B=chunk c) ----
    for (int c = 1; c < NW; ++c) {
        float B1i  = sig1[c][i];
        float B1j  = sig1[c][j];
        float B2ij = sig2[c][lane];
        float4 b1a = *(const float4*)&sig1[c][0];
        float4 b1b = *(const float4*)&sig1[c][4];
        const float* b2row = &sig2[c][j * 8];
        float4 b2a = *(const float4*)(b2row);
        float4 b2b = *(const float4*)(b2row + 4);
        const float* b3row = &sig3[c][lane * 8];
        float4 b3a = *(const float4*)(b3row);
        float4 b3b = *(const float4*)(b3row + 4);
        float B1k[8]  = {b1a.x, b1a.y, b1a.z, b1a.w, b1b.x, b1b.y, b1b.z, b1b.w};
        float B2jk[8] = {b2a.x, b2a.y, b2a.z, b2a.w, b2b.x, b2b.y, b2b.z, b2b.w};
        float B3[8]   = {b3a.x, b3a.y, b3a.z, b3a.w, b3b.x, b3b.y, b3b.z, b3b.w};
#pragma unroll
        for (int k = 0; k < 8; ++k)   // uses OLD s1 (A1), OLD s2 (A2)
            s3[k] = s3[k] + B3[k] + s1 * B2jk[k] + s2 * B1k[k];
        s2 = s2 + B2ij + s1 * B1j;    // uses OLD s1
        s1 = s1 + B1i;
    }

    // ---- Log map epilogue (wave-internal LDS exchange) ----
    if (j == 0) s1buf[i] = s1;
    s2buf[lane] = s2;

    float S1r[8], S2rj[8];
#pragma unroll
    for (int k = 0; k < 8; ++k) S1r[k] = s1buf[k];
#pragma unroll
    for (int k = 0; k < 8; ++k) S2rj[k] = s2buf[j * 8 + k];
    float s1j = s1buf[j];

    float* ob = out + (size_t)b * OUTSTRIDE;
    if (lane < 8) ob[lane] = s1buf[lane];            // l1
    ob[8 + lane] = fmaf(-0.5f * s1, s1j, s2);        // l2

    float c3 = (1.f / 3.f) * s1 * s1j;
    float l3[8];
#pragma unroll
    for (int k = 0; k < 8; ++k)
        l3[k] = s3[k] - 0.5f * (s1 * S2rj[k] + s2 * S1r[k]) + c3 * S1r[k];
    float* p3 = ob + 72 + lane * 8;
    *(float4*)(p3)     = make_float4(l3[0], l3[1], l3[2], l3[3]);
    *(float4*)(p3 + 4) = make_float4(l3[4], l3[5], l3[6], l3[7]);
}

extern "C" void kernel_launch(void* const* d_in, const int* in_sizes, int n_in,
                              void* d_out, int out_size, void* d_ws, size_t ws_size,
                              hipStream_t stream) {
    const float* x = (const float*)d_in[0];
    float* out = (float*)d_out;
    const int B = in_sizes[0] / (LEN * DCH);   // 2048
    hipLaunchKernelGGL(logsig_fused, dim3(B), dim3(256), 0, stream, x, out);
}